// Round 14
// baseline (1253.960 us; speedup 1.0000x reference)
//
#include <hip/hip_runtime.h>
#include <hip/hip_bf16.h>

typedef unsigned short u16;
typedef __attribute__((ext_vector_type(8))) short bhalf8;
typedef __attribute__((ext_vector_type(4))) short bhalf4;
typedef __attribute__((ext_vector_type(4))) float f32x4;

__device__ inline f32x4 mfma_bf16(bhalf8 a, bhalf8 b, f32x4 c) {
    return __builtin_amdgcn_mfma_f32_16x16x32_bf16(a, b, c, 0, 0, 0);
}
__device__ inline f32x4 mfma16_bf16(bhalf4 a, bhalf4 b, f32x4 c) {
    return __builtin_amdgcn_mfma_f32_16x16x16bf16_1k(a, b, c, 0, 0, 0);
}

__device__ inline u16 f2bf(float f) {
    union { float f; unsigned u; } v; v.f = f;
    unsigned u = v.u;
    return (u16)((u + 0x7fff + ((u >> 16) & 1)) >> 16);
}
// HW packed fp32x2 -> bf16x2 (lo = a, hi = b)
__device__ inline unsigned cvtpk(float a, float b) {
    unsigned d;
    asm("v_cvt_pk_bf16_f32 %0, %1, %2" : "=v"(d) : "v"(a), "v"(b));
    return d;
}

// Fragment-major (afm) layout for [M][C] bf16: tile t=row>>4, chunk kc=col>>5,
// lane' = (row&15) + 16*((col>>3)&3), elem i = col&7.
__device__ inline size_t afm_off(int row, int col, int Cc) {
    return ((size_t)((row >> 4) * Cc + (col >> 5))) * 512
         + (((row & 15) + 16 * ((col >> 3) & 3)) << 3) + (col & 7);
}

// ---------------- prologue kernels ----------------

__global__ __launch_bounds__(256) void k_wtrans_fm(const float* in, u16* out, int rows, int cols) {
    int mat = blockIdx.y;
    size_t rc = (size_t)rows * cols;
    size_t idx = (size_t)blockIdx.x * 256 + threadIdx.x;
    if (idx >= rc) return;
    int r = (int)(idx / cols), c = (int)(idx % cols);   // r=k, c=n
    size_t off = ((size_t)((c >> 4) * (rows >> 5) + (r >> 5))) * 512
               + (((c & 15) + 16 * ((r >> 3) & 3)) << 3) + (r & 7);
    out[mat * rc + off] = f2bf(in[mat * rc + idx]);
}

__global__ __launch_bounds__(256) void k_addpos(const float* x, const float* pos, u16* xp) {
    size_t idx = (size_t)blockIdx.x * 256 + threadIdx.x;
    size_t p = idx & ((size_t)4096 * 256 - 1);
    int row = (int)(idx >> 8), col = (int)(idx & 255);
    xp[afm_off(row, col, 8)] = f2bf(x[idx] + pos[p]);
}

__global__ __launch_bounds__(256) void k_inith(const float* y, float* h, u16* hb) {
    size_t idx = (size_t)blockIdx.x * 256 + threadIdx.x;
    float v = y[idx];
    h[idx] = v;
    int row = (int)(idx >> 8), col = (int)(idx & 255);
    hb[afm_off(row, col, 8)] = f2bf(v);
}

// ---------------- QKV GEMM (all operands fragment-major) ----------------
__global__ __launch_bounds__(256) void k_gemm_qkv(const u16* A0, const u16* A2,
                                                  const u16* Wfm0, const float* bias0,
                                                  u16* qout, u16* kfm_out, u16* vfm_out,
                                                  int K, long wz, long bz, float scale0,
                                                  int kz, int vz, int Skv, int M0) {
    int z = blockIdx.z;
    int wave = threadIdx.x >> 6, lane = threadIdx.x & 63;
    int l16 = lane & 15, quad = lane >> 4;
    int row0 = blockIdx.x * 64 + wave * 16;
    int col0 = blockIdx.y * 32;
    const u16* A;
    if (z == 0) { if (row0 >= M0) return; A = A0; } else { A = A2; }
    const u16* Wfm = Wfm0 + (size_t)z * wz;
    const float* bias = bias0 + (size_t)z * bz;
    int Kc = K >> 5;

    f32x4 acc0 = (f32x4){0.f, 0.f, 0.f, 0.f};
    f32x4 acc1 = (f32x4){0.f, 0.f, 0.f, 0.f};
    const u16* ab = A + (size_t)(row0 >> 4) * Kc * 512 + lane * 8;
    const u16* wb0 = Wfm + (size_t)(col0 >> 4) * Kc * 512 + lane * 8;
    const u16* wb1 = wb0 + (size_t)Kc * 512;
    #pragma unroll 4
    for (int kc = 0; kc < Kc; kc++) {
        bhalf8 a = *(const bhalf8*)(ab + kc * 512);
        acc0 = mfma_bf16(a, *(const bhalf8*)(wb0 + kc * 512), acc0);
        acc1 = mfma_bf16(a, *(const bhalf8*)(wb1 + kc * 512), acc1);
    }

    f32x4 accs[2] = {acc0, acc1};
    #pragma unroll
    for (int nt = 0; nt < 2; nt++) {
        int col = col0 + nt * 16 + l16;
        float bs = bias[col];
        if (z == kz) {
            int hh = col >> 6, dim = col & 63;
            int f = dim >> 5, q8 = (dim >> 3) & 3, i8 = dim & 7;
            #pragma unroll
            for (int r = 0; r < 4; r++) {
                int row = row0 + quad * 4 + r;
                int bb = row / Skv; int key = row - bb * Skv;
                size_t off = (size_t)(bb * 4 + hh) * Skv * 64 + (size_t)(key >> 4) * 1024
                           + f * 512 + q8 * 128 + (key & 15) * 8 + i8;
                kfm_out[off] = f2bf(accs[nt][r] + bs);
            }
        } else if (z == vz) {
            int hh = col >> 6, dim = col & 63;
            int ntg = dim >> 4, l16v = dim & 15;
            int row = row0 + quad * 4;
            int bb = row / Skv; int key = row - bb * Skv;
            size_t off = (size_t)(bb * 4 + hh) * Skv * 64 + (size_t)(key >> 4) * 1024
                       + ntg * 256 + ((key & 15) >> 2) * 64 + l16v * 4;
            ushort4 pk;
            pk.x = f2bf(accs[nt][0] + bs);
            pk.y = f2bf(accs[nt][1] + bs);
            pk.z = f2bf(accs[nt][2] + bs);
            pk.w = f2bf(accs[nt][3] + bs);
            *(ushort4*)(vfm_out + off) = pk;
        } else {
            size_t base = ((size_t)(row0 >> 4) * 8 + blockIdx.y) * 512;
            int g3 = (nt * 2 + (l16 >> 3)) & 3;
            int i = l16 & 7;
            #pragma unroll
            for (int r = 0; r < 4; r++)
                qout[base + (((quad * 4 + r) + 16 * g3) << 3) + i] =
                    f2bf((accs[nt][r] + bs) * scale0);
        }
    }
}

// ---------------- GEMM + bias + residual + LayerNorm (8 waves) ----------------
__global__ __launch_bounds__(512) void k_gemm_ln(const u16* A, const u16* Wfm, const float* bias,
                                                 const float* res, const float* g, const float* beta,
                                                 float* outf, u16* outb, int K) {
    int t = threadIdx.x;
    int w = t >> 6, lane = t & 63;
    int l16 = lane & 15, quad = lane >> 4;
    int row0 = blockIdx.x * 16;
    int Kc = K >> 5;

    f32x4 acc[2];
    acc[0] = (f32x4){0.f, 0.f, 0.f, 0.f};
    acc[1] = (f32x4){0.f, 0.f, 0.f, 0.f};

    const u16* ab = A + (size_t)blockIdx.x * Kc * 512 + lane * 8;
    const u16* wb = Wfm + (size_t)(w * 2) * Kc * 512 + lane * 8;
    #pragma unroll 4
    for (int kc = 0; kc < Kc; kc++) {
        bhalf8 a = *(const bhalf8*)(ab + kc * 512);
        acc[0] = mfma_bf16(a, *(const bhalf8*)(wb + kc * 512), acc[0]);
        acc[1] = mfma_bf16(a, *(const bhalf8*)(wb + (size_t)(Kc + kc) * 512), acc[1]);
    }

    float sr[4] = {0.f, 0.f, 0.f, 0.f}, s2r[4] = {0.f, 0.f, 0.f, 0.f};
    #pragma unroll
    for (int nt = 0; nt < 2; nt++) {
        int col = w * 32 + nt * 16 + l16;
        float bs = bias[col];
        #pragma unroll
        for (int r = 0; r < 4; r++) {
            int row = row0 + quad * 4 + r;
            float v = acc[nt][r] + bs + res[(size_t)row * 256 + col];
            acc[nt][r] = v;
            sr[r] += v; s2r[r] += v * v;
        }
    }
    #pragma unroll
    for (int r = 0; r < 4; r++) {
        #pragma unroll
        for (int off = 8; off >= 1; off >>= 1) {
            sr[r]  += __shfl_xor(sr[r], off, 16);
            s2r[r] += __shfl_xor(s2r[r], off, 16);
        }
    }
    __shared__ float lsm[8][16], lsq[8][16];
    if (l16 == 0) {
        #pragma unroll
        for (int r = 0; r < 4; r++) { lsm[w][quad * 4 + r] = sr[r]; lsq[w][quad * 4 + r] = s2r[r]; }
    }
    __syncthreads();
    float mu[4], rs[4];
    #pragma unroll
    for (int r = 0; r < 4; r++) {
        int ri = quad * 4 + r;
        float ts = 0.f, tq = 0.f;
        #pragma unroll
        for (int ww = 0; ww < 8; ww++) { ts += lsm[ww][ri]; tq += lsq[ww][ri]; }
        mu[r] = ts * (1.f / 256.f);
        float var = tq * (1.f / 256.f) - mu[r] * mu[r];
        rs[r] = rsqrtf(var + 1e-12f);
    }
    size_t base = ((size_t)blockIdx.x * 8 + w) * 512;
    #pragma unroll
    for (int nt = 0; nt < 2; nt++) {
        int col = w * 32 + nt * 16 + l16;
        float gc = g[col], bc = beta[col];
        int g3 = (nt * 2 + (l16 >> 3)) & 3;
        int i = l16 & 7;
        #pragma unroll
        for (int r = 0; r < 4; r++) {
            int row = row0 + quad * 4 + r;
            float yv = (acc[nt][r] - mu[r]) * rs[r] * gc + bc;
            outf[(size_t)row * 256 + col] = yv;
            outb[base + (((quad * 4 + r) + 16 * g3) << 3) + i] = f2bf(yv);
        }
    }
}

// ---------------- fused FFN: GEMM1+GELU -> LDS -> GEMM2 + res + LN -----------
__global__ __launch_bounds__(512) void k_ffn(const u16* A, const u16* W1, const float* b1,
                                             const u16* W2, const float* b2,
                                             const float* res, const float* g, const float* beta,
                                             float* outf, u16* outb) {
    int t = threadIdx.x;
    int w = t >> 6, lane = t & 63;
    int l16 = lane & 15, quad = lane >> 4;
    int row0 = blockIdx.x * 16;

    __shared__ u16 f1lds[32 * 512];
    __shared__ float lsm[8][16], lsq[8][16];

    f32x4 acc[8];
    #pragma unroll
    for (int nt = 0; nt < 8; nt++) acc[nt] = (f32x4){0.f, 0.f, 0.f, 0.f};
    const u16* ab = A + (size_t)blockIdx.x * 8 * 512 + lane * 8;
    const u16* w1b = W1 + (size_t)(w * 8) * 8 * 512 + lane * 8;
    #pragma unroll
    for (int kc = 0; kc < 8; kc++) {
        bhalf8 a = *(const bhalf8*)(ab + kc * 512);
        #pragma unroll
        for (int nt = 0; nt < 8; nt++)
            acc[nt] = mfma_bf16(a, *(const bhalf8*)(w1b + ((size_t)nt * 8 + kc) * 512), acc[nt]);
    }
    #pragma unroll
    for (int nt = 0; nt < 8; nt++) {
        int col = w * 128 + nt * 16 + l16;
        float bs = b1[col];
        int chunk = w * 4 + (nt >> 1);
        int g3 = (nt * 2 + (l16 >> 3)) & 3;
        int i = l16 & 7;
        #pragma unroll
        for (int r = 0; r < 4; r++) {
            float v = acc[nt][r] + bs;
            float ge = 0.5f * v * (1.f + tanhf(0.7978845608028654f * (v + 0.044715f * v * v * v)));
            f1lds[chunk * 512 + (((quad * 4 + r) + 16 * g3) << 3) + i] = f2bf(ge);
        }
    }
    __syncthreads();

    f32x4 acc2[2];
    acc2[0] = (f32x4){0.f, 0.f, 0.f, 0.f};
    acc2[1] = (f32x4){0.f, 0.f, 0.f, 0.f};
    const u16* w2b = W2 + (size_t)(w * 2) * 32 * 512 + lane * 8;
    #pragma unroll 4
    for (int kc = 0; kc < 32; kc++) {
        bhalf8 a = *(const bhalf8*)&f1lds[kc * 512 + lane * 8];
        acc2[0] = mfma_bf16(a, *(const bhalf8*)(w2b + (size_t)kc * 512), acc2[0]);
        acc2[1] = mfma_bf16(a, *(const bhalf8*)(w2b + (size_t)(32 + kc) * 512), acc2[1]);
    }

    float sr[4] = {0.f, 0.f, 0.f, 0.f}, s2r[4] = {0.f, 0.f, 0.f, 0.f};
    #pragma unroll
    for (int nt = 0; nt < 2; nt++) {
        int col = w * 32 + nt * 16 + l16;
        float bs = b2[col];
        #pragma unroll
        for (int r = 0; r < 4; r++) {
            int row = row0 + quad * 4 + r;
            float v = acc2[nt][r] + bs + res[(size_t)row * 256 + col];
            acc2[nt][r] = v;
            sr[r] += v; s2r[r] += v * v;
        }
    }
    #pragma unroll
    for (int r = 0; r < 4; r++) {
        #pragma unroll
        for (int off = 8; off >= 1; off >>= 1) {
            sr[r]  += __shfl_xor(sr[r], off, 16);
            s2r[r] += __shfl_xor(s2r[r], off, 16);
        }
    }
    if (l16 == 0) {
        #pragma unroll
        for (int r = 0; r < 4; r++) { lsm[w][quad * 4 + r] = sr[r]; lsq[w][quad * 4 + r] = s2r[r]; }
    }
    __syncthreads();
    float mu[4], rs[4];
    #pragma unroll
    for (int r = 0; r < 4; r++) {
        int ri = quad * 4 + r;
        float ts = 0.f, tq = 0.f;
        #pragma unroll
        for (int ww = 0; ww < 8; ww++) { ts += lsm[ww][ri]; tq += lsq[ww][ri]; }
        mu[r] = ts * (1.f / 256.f);
        float var = tq * (1.f / 256.f) - mu[r] * mu[r];
        rs[r] = rsqrtf(var + 1e-12f);
    }
    size_t base = ((size_t)blockIdx.x * 8 + w) * 512;
    #pragma unroll
    for (int nt = 0; nt < 2; nt++) {
        int col = w * 32 + nt * 16 + l16;
        float gc = g[col], bc = beta[col];
        int g3 = (nt * 2 + (l16 >> 3)) & 3;
        int i = l16 & 7;
        #pragma unroll
        for (int r = 0; r < 4; r++) {
            int row = row0 + quad * 4 + r;
            float yv = (acc2[nt][r] - mu[r]) * rs[r] * gc + bc;
            outf[(size_t)row * 256 + col] = yv;
            outb[base + (((quad * 4 + r) + 16 * g3) << 3) + i] = f2bf(yv);
        }
    }
}

// ---------------- flash attention v11: 2 q-tiles/wave + cvt_pk ----------------
// Block 256 thr = 4 kw-waves; each wave owns 32 q rows (2 tiles) x Sk/4 keys.
// K/V fragments loaded once per wave-tile serve both q-tiles (halves L2 traffic).
// P-pack via v_cvt_pk_bf16_f32. Fixed-shift softmax exp2(s - 8*log2e), exact.
__global__ __launch_bounds__(256, 4) void k_attn(const u16* q, const u16* kfm, const u16* vfm,
                                                 u16* ctx, int Sq, int Sk) {
    int bh = blockIdx.x & 7;
    int b = bh >> 2, h = bh & 3;
    int qt2 = blockIdx.x >> 3;
    int t = threadIdx.x;
    int kw = t >> 6, lane = t & 63;
    int l16 = lane & 15, quad = lane >> 4;
    int q0 = qt2 * 32;

    __shared__ float opart[2][3][64][17];
    __shared__ float lsum[2][3][16];

    // Q fragments for both q-tiles (afm)
    const u16* qbA = q + (((size_t)((b * Sq + q0) >> 4)) * 8 + h * 2) * 512 + lane * 8;
    bhalf8 bqA0 = *(const bhalf8*)(qbA);
    bhalf8 bqA1 = *(const bhalf8*)(qbA + 512);
    const u16* qbB = qbA + 8 * 512;
    bhalf8 bqB0 = *(const bhalf8*)(qbB);
    bhalf8 bqB1 = *(const bhalf8*)(qbB + 512);

    const u16* kwb = kfm + (size_t)(b * 4 + h) * Sk * 64;
    const u16* vwb = vfm + (size_t)(b * 4 + h) * Sk * 64;

    int nT = Sk >> 6;          // 16-key tiles per kw wave
    int T0 = kw * nT;

    float lA = 0.f, lB = 0.f;
    f32x4 oA[4], oB[4];
    #pragma unroll
    for (int nt = 0; nt < 4; nt++) {
        oA[nt] = (f32x4){0.f, 0.f, 0.f, 0.f};
        oB[nt] = (f32x4){0.f, 0.f, 0.f, 0.f};
    }

    #pragma unroll 2
    for (int T = T0; T < T0 + nT; T++) {
        const u16* kt = kwb + (size_t)T * 1024;
        bhalf8 a0 = *(const bhalf8*)(kt + lane * 8);
        bhalf8 a1 = *(const bhalf8*)(kt + 512 + lane * 8);
        f32x4 sA = (f32x4){0.f, 0.f, 0.f, 0.f};
        f32x4 sB = (f32x4){0.f, 0.f, 0.f, 0.f};
        sA = mfma_bf16(a0, bqA0, sA);
        sA = mfma_bf16(a1, bqA1, sA);
        sB = mfma_bf16(a0, bqB0, sB);
        sB = mfma_bf16(a1, bqB1, sB);

        float pA[4], pB[4], psA = 0.f, psB = 0.f;
        #pragma unroll
        for (int r = 0; r < 4; r++) {
            pA[r] = exp2f(sA[r] - 11.5415603f);
            pB[r] = exp2f(sB[r] - 11.5415603f);
            psA += pA[r]; psB += pB[r];
        }
        lA += psA; lB += psB;

        union { bhalf4 v; unsigned u[2]; } bpA, bpB;
        bpA.u[0] = cvtpk(pA[0], pA[1]); bpA.u[1] = cvtpk(pA[2], pA[3]);
        bpB.u[0] = cvtpk(pB[0], pB[1]); bpB.u[1] = cvtpk(pB[2], pB[3]);

        const u16* vts = vwb + (size_t)T * 1024 + quad * 64 + l16 * 4;
        #pragma unroll
        for (int nt = 0; nt < 4; nt++) {
            bhalf4 va = *(const bhalf4*)(vts + nt * 256);
            oA[nt] = mfma16_bf16(va, bpA.v, oA[nt]);
            oB[nt] = mfma16_bf16(va, bpB.v, oB[nt]);
        }
    }

    float lcA = lA, lcB = lB;
    lcA += __shfl_xor(lcA, 16, 64); lcA += __shfl_xor(lcA, 32, 64);
    lcB += __shfl_xor(lcB, 16, 64); lcB += __shfl_xor(lcB, 32, 64);

    if (kw > 0) {
        #pragma unroll
        for (int nt = 0; nt < 4; nt++)
            #pragma unroll
            for (int r = 0; r < 4; r++) {
                opart[0][kw - 1][nt * 16 + quad * 4 + r][l16] = oA[nt][r];
                opart[1][kw - 1][nt * 16 + quad * 4 + r][l16] = oB[nt][r];
            }
        if (quad == 0) { lsum[0][kw - 1][l16] = lcA; lsum[1][kw - 1][l16] = lcB; }
    }
    __syncthreads();
    if (kw == 0) {
        float LA = lcA + lsum[0][0][l16] + lsum[0][1][l16] + lsum[0][2][l16];
        float LB = lcB + lsum[1][0][l16] + lsum[1][1][l16] + lsum[1][2][l16];
        float invLA = 1.f / LA, invLB = 1.f / LB;
        size_t rowt = (size_t)((b * Sq + q0) >> 4);
        #pragma unroll
        for (int nt = 0; nt < 4; nt++) {
            ushort4 pkvA, pkvB;
            #pragma unroll
            for (int r = 0; r < 4; r++) {
                float vA = oA[nt][r] + opart[0][0][nt * 16 + quad * 4 + r][l16]
                                     + opart[0][1][nt * 16 + quad * 4 + r][l16]
                                     + opart[0][2][nt * 16 + quad * 4 + r][l16];
                float vB = oB[nt][r] + opart[1][0][nt * 16 + quad * 4 + r][l16]
                                     + opart[1][1][nt * 16 + quad * 4 + r][l16]
                                     + opart[1][2][nt * 16 + quad * 4 + r][l16];
                ((u16*)&pkvA)[r] = f2bf(vA * invLA);
                ((u16*)&pkvB)[r] = f2bf(vB * invLB);
            }
            size_t soff = ((l16 + 16 * ((nt * 2 + (quad >> 1)) & 3)) << 3) + (quad & 1) * 4;
            *(ushort4*)(ctx + (rowt * 8 + (h * 2 + (nt >> 1))) * 512 + soff) = pkvA;
            *(ushort4*)(ctx + ((rowt + 1) * 8 + (h * 2 + (nt >> 1))) * 512 + soff) = pkvB;
        }
    }
}

// ---------------- host ----------------
extern "C" void kernel_launch(void* const* d_in, const int* in_sizes, int n_in,
                              void* d_out, int out_size, void* d_ws, size_t ws_size,
                              hipStream_t stream) {
    const float* x        = (const float*)d_in[0];
    const float* y        = (const float*)d_in[1];
    const float* pos      = (const float*)d_in[2];
    const float* sqkv_w   = (const float*)d_in[3];
    const float* sqkv_b   = (const float*)d_in[4];
    const float* so_w     = (const float*)d_in[5];
    const float* so_b     = (const float*)d_in[6];
    const float* cqkv_w   = (const float*)d_in[7];
    const float* cqkv_b   = (const float*)d_in[8];
    const float* co_w     = (const float*)d_in[9];
    const float* co_b     = (const float*)d_in[10];
    const float* ffn_w1   = (const float*)d_in[11];
    const float* ffn_b1   = (const float*)d_in[12];
    const float* ffn_w2   = (const float*)d_in[13];
    const float* ffn_b2   = (const float*)d_in[14];
    const float* ln_g     = (const float*)d_in[15];
    const float* ln_b     = (const float*)d_in[16];

    char* w = (char*)d_ws;
    auto alloc = [&](size_t bytes) { char* p = w; w += (bytes + 255) & ~(size_t)255; return p; };

    u16* wt_sqkv = (u16*)alloc(18ull * 65536 * 2);
    u16* wt_so   = (u16*)alloc(6ull  * 65536 * 2);
    u16* wt_cqkv = (u16*)alloc(18ull * 65536 * 2);
    u16* wt_co   = (u16*)alloc(6ull  * 65536 * 2);
    u16* wt_f1   = (u16*)alloc(6ull  * 262144 * 2);
    u16* wt_f2   = (u16*)alloc(6ull  * 262144 * 2);
    u16* xp      = (u16*)alloc(2097152ull * 2);
    float* hf    = (float*)alloc(1048576ull * 4);
    u16* hb      = (u16*)alloc(1048576ull * 2);
    u16* qbuf    = (u16*)alloc(1048576ull * 2);
    u16* kfm     = (u16*)alloc(2097152ull * 2);
    u16* vfm     = (u16*)alloc(2097152ull * 2);
    u16* ctx     = (u16*)alloc(1048576ull * 2);

    k_wtrans_fm<<<dim3(256, 18), 256, 0, stream>>>(sqkv_w, wt_sqkv, 256, 256);
    k_wtrans_fm<<<dim3(256, 6),  256, 0, stream>>>(so_w,   wt_so,   256, 256);
    k_wtrans_fm<<<dim3(256, 18), 256, 0, stream>>>(cqkv_w, wt_cqkv, 256, 256);
    k_wtrans_fm<<<dim3(256, 6),  256, 0, stream>>>(co_w,   wt_co,   256, 256);
    k_wtrans_fm<<<dim3(1024, 6), 256, 0, stream>>>(ffn_w1, wt_f1,   256, 1024);
    k_wtrans_fm<<<dim3(1024, 6), 256, 0, stream>>>(ffn_w2, wt_f2,   1024, 256);
    k_addpos<<<dim3(8192), 256, 0, stream>>>(x, pos, xp);
    k_inith<<<dim3(4096), 256, 0, stream>>>(y, hf, hb);

    const float qscale = 0.125f * 1.44269504f;  // 1/sqrt(64) * log2(e)

    for (int i = 0; i < 6; i++) {
        // ---- self attention ----
        k_gemm_qkv<<<dim3(64, 8, 3), 256, 0, stream>>>(hb, hb,
            wt_sqkv + (size_t)i * 3 * 65536, sqkv_b + i * 768,
            qbuf, kfm, vfm, 256, 65536, 256, qscale, 1, 2, 2048, 4096);
        k_attn<<<dim3(512), 256, 0, stream>>>(qbuf, kfm, vfm, ctx, 2048, 2048);
        k_gemm_ln<<<dim3(256), 512, 0, stream>>>(ctx, wt_so + (size_t)i * 65536,
            so_b + i * 256, hf, ln_g + (i * 3 + 0) * 256, ln_b + (i * 3 + 0) * 256,
            hf, hb, 256);

        // ---- cross attention ----
        k_gemm_qkv<<<dim3(128, 8, 3), 256, 0, stream>>>(hb, xp,
            wt_cqkv + (size_t)i * 3 * 65536, cqkv_b + i * 768,
            qbuf, kfm, vfm, 256, 65536, 256, qscale, 1, 2, 4096, 4096);
        k_attn<<<dim3(512), 256, 0, stream>>>(qbuf, kfm, vfm, ctx, 2048, 4096);
        k_gemm_ln<<<dim3(256), 512, 0, stream>>>(ctx, wt_co + (size_t)i * 65536,
            co_b + i * 256, hf, ln_g + (i * 3 + 1) * 256, ln_b + (i * 3 + 1) * 256,
            hf, hb, 256);

        // ---- fused FFN ----
        float* dst = (i == 5) ? (float*)d_out : hf;
        k_ffn<<<dim3(256), 512, 0, stream>>>(hb, wt_f1 + (size_t)i * 262144,
            ffn_b1 + i * 1024, wt_f2 + (size_t)i * 262144, ffn_b2 + i * 256,
            hf, ln_g + (i * 3 + 2) * 256, ln_b + (i * 3 + 2) * 256, dst, hb);
    }
}